// Round 8
// baseline (606.610 us; speedup 1.0000x reference)
//
#include <hip/hip_runtime.h>
#include <hip/hip_bf16.h>

#define BB 2
#define SS 2048
#define HH 1024
#define EE 8
#define KK 2
#define CAP 1536
#define NTOK (BB * SS)        // 4096
#define NASSIGN (NTOK * KK)   // 8192

// ---------------- workspace layout (float indices) ----------------
#define WS_PSUM   0            // 8
#define WS_CTR    8            // 3 ints: hc-done[b0], hc-done[b1], logits-done
#define WS_AVG    16           // (fallback path partial region unused here)
#define WS_HC     2056         // 2048  (hc_raw)
#define WS_ADJ    4104         // 16
#define WS_P1     4120         // 4096
#define WS_P2     8216         // 4096
#define WS_IDX    12312        // 4096 ints
#define WS_LOGITS 16408        // 32768: fallback logits OR avg partials (16*2*1024)
#define WS_ZERO_FLOATS 4112    // psum+ctr+...+hc+adj head (zeroed by prep blk0 / memset)
#define WS_ZERO_BYTES 16448
#define WS_BF16_BYTE 196704    // bf16 planes start here (16B aligned)
// planes: Xh/Xm/Xl 3*8388608 B + Wh/Wm/Wl 3*2097152 B = 31457280 B
#define WS_H_BYTE (WS_BF16_BYTE + 31457280)   // h fp32: 16777216 B
#define WS_NEED (WS_H_BYTE + 16777216ull)

using short8 = __attribute__((ext_vector_type(8))) short;
using u16x8  = __attribute__((ext_vector_type(8))) unsigned short;
using f32x4  = __attribute__((ext_vector_type(4))) float;

// ---- bf16 split helpers (manual RNE) ----
__device__ __forceinline__ unsigned short f2bf(float f) {
  unsigned u = __float_as_uint(f);
  unsigned r = (u + 0x7fffu + ((u >> 16) & 1u)) >> 16;
  return (unsigned short)r;
}
__device__ __forceinline__ float bf2f(unsigned short h) {
  return __uint_as_float((unsigned)h << 16);
}
__device__ __forceinline__ void split3(float x, unsigned short& h,
                                       unsigned short& m, unsigned short& l) {
  h = f2bf(x);
  float r = x - bf2f(h);
  m = f2bf(r);
  l = f2bf(r - bf2f(m));
}

// async global->LDS, 16B per lane; lptr is wave-uniform base, HW adds lane*16
__device__ __forceinline__ void gload_lds16(const void* g, void* l) {
  __builtin_amdgcn_global_load_lds(
      (const __attribute__((address_space(1))) void*)g,
      (__attribute__((address_space(3))) void*)l, 16, 0, 0);
}

// ---------------- D1: consolidated prep dispatch ----------------
// blocks [0,4096): split X -> bf16 planes (blk0 also zeros ws scalar head)
// blocks [4096,4352): split+transpose w1 -> bf16 planes
// blocks [4352,4480): avg partial sums (no atomics, no zero-init needed)
#define PREPX_BLKS 4096
#define PREPW_BLKS 256
#define AVG_BLKS   128
__global__ __launch_bounds__(256) void k_prep(
    const float* __restrict__ x, const float* __restrict__ w1,
    unsigned short* __restrict__ Xh, unsigned short* __restrict__ Xm,
    unsigned short* __restrict__ Xl,
    unsigned short* __restrict__ Wh, unsigned short* __restrict__ Wm,
    unsigned short* __restrict__ Wl,
    float* __restrict__ wshead, float* __restrict__ avg_part) {
  __shared__ unsigned short Th[64 * 65], Tm[64 * 65], Tl[64 * 65];
  int tid = threadIdx.x;
  int bid = blockIdx.x;
  if (bid < PREPX_BLKS) {
    if (bid == 0)
      for (int j = tid; j < WS_ZERO_FLOATS; j += 256) wshead[j] = 0.f;
    int i = (bid * 256 + tid) * 4;
    float4 v = *(const float4*)&x[i];
    unsigned short h[4], m[4], l[4];
    split3(v.x, h[0], m[0], l[0]);
    split3(v.y, h[1], m[1], l[1]);
    split3(v.z, h[2], m[2], l[2]);
    split3(v.w, h[3], m[3], l[3]);
    *(ushort4*)&Xh[i] = make_ushort4(h[0], h[1], h[2], h[3]);
    *(ushort4*)&Xm[i] = make_ushort4(m[0], m[1], m[2], m[3]);
    *(ushort4*)&Xl[i] = make_ushort4(l[0], l[1], l[2], l[3]);
  } else if (bid < PREPX_BLKS + PREPW_BLKS) {
    int pid = bid - PREPX_BLKS;
    int k0 = (pid & 15) * 64, n0 = (pid >> 4) * 64;
    for (int i = 0; i < 16; ++i) {
      int e = i * 256 + tid;
      int k = e >> 6, n = e & 63;
      float v = w1[(size_t)(k0 + k) * HH + n0 + n];
      unsigned short h, m, l;
      split3(v, h, m, l);
      Th[n * 65 + k] = h; Tm[n * 65 + k] = m; Tl[n * 65 + k] = l;
    }
    __syncthreads();
    for (int i = 0; i < 16; ++i) {
      int e = i * 256 + tid;
      int n = e >> 6, k = e & 63;
      size_t o = (size_t)(n0 + n) * HH + k0 + k;
      Wh[o] = Th[n * 65 + k]; Wm[o] = Tm[n * 65 + k]; Wl[o] = Tl[n * 65 + k];
    }
  } else {
    int pid = bid - PREPX_BLKS - PREPW_BLKS;  // 0..127
    int h = (pid & 3) * 256 + tid;
    int c = (pid >> 2) & 15;
    int b = pid >> 6;
    const float* p = x + (size_t)b * SS * HH + (size_t)(c * 128) * HH + h;
    float s = 0.f;
    for (int i = 0; i < 128; ++i) s += p[(size_t)i * HH];
    avg_part[(c * BB + b) * HH + h] = s;   // raw partial sum
  }
}

// ---------------- D2: MFMA GEMM + output zeroing + hc/adj side-chain -------
// Grid (32,17): y<16 -> 512 GEMM blocks (R5 structure: in-loop NT zero
// stores of disp/comb drain behind MFMA; NT keeps bf16 planes in L2/L3).
// y==16 -> 32 hc blocks (16 per batch, 64 cols each), barrier-free wrt GEMM,
// hidden under the ~90us GEMM; per-b last-arrival block computes adj inline.
#define BM 128
#define BN 64
#define BK 32
#define ZF4_PER_BLOCK 49152   // 25165824 f4 / 512 gemm blocks
__global__ __launch_bounds__(256) void k_gemm_mfma(
    const unsigned short* __restrict__ Xh, const unsigned short* __restrict__ Xm,
    const unsigned short* __restrict__ Xl,
    const unsigned short* __restrict__ Wh, const unsigned short* __restrict__ Wm,
    const unsigned short* __restrict__ Wl,
    const float* __restrict__ b1, float* __restrict__ hbuf,
    f32x4* __restrict__ zout,
    const float* __restrict__ avg_part, const float* __restrict__ chr,
    const float* __restrict__ wc1, const float* __restrict__ bc1,
    const float* __restrict__ wc2, const float* __restrict__ bc2,
    float* __restrict__ hc_raw, float* __restrict__ adj,
    int* __restrict__ ctr) {
  __shared__ unsigned short As[3][BM * BK];   // 3 x 8KB
  __shared__ unsigned short Bs[3][BN * BK];   // 3 x 4KB
  __shared__ float b1s[BN];
  __shared__ float red[4][EE];
  __shared__ int sflag;
  int tid = threadIdx.x;

  if (blockIdx.y == HH / BN) {   // ---- hc blocks ----
    int b  = blockIdx.x & 1;
    int j0 = (blockIdx.x >> 1) * 64;
    float* avgs  = (float*)&As[0][0];   // 4KB alias (staging unused here)
    float* hcred = (float*)&Bs[0][0];   // 1KB alias
    // reduce the 16 avg partials -> avgs[0..1023] (scaled)
    for (int k = 0; k < 4; ++k) {
      int i = tid * 4 + k;
      float s = 0.f;
#pragma unroll
      for (int cc = 0; cc < 16; ++cc) s += avg_part[(cc * BB + b) * HH + i];
      avgs[i] = s * (1.0f / SS);
    }
    __syncthreads();
    // hc[j0+jj] = dot over 1032 rows of wc1, split 4 ways
    int p = tid >> 6, jj = tid & 63, j = j0 + jj;
    float acc = 0.f;
    for (int i = p * 258; i < p * 258 + 258; ++i) {
      float a = (i < HH) ? avgs[i] : chr[i - HH];
      acc += a * wc1[(size_t)i * HH + j];
    }
    hcred[p * 64 + jj] = acc;
    __syncthreads();
    if (tid < 64) {
      float s = hcred[tid] + hcred[64 + tid] + hcred[128 + tid] + hcred[192 + tid];
      hc_raw[b * HH + j0 + tid] = s;
    }
    __threadfence();
    __syncthreads();
    if (tid == 0) sflag = (atomicAdd(&ctr[b], 1) == 15);
    __syncthreads();
    if (!sflag) return;
    __threadfence();
    // last block for this b: adj = tanh(relu(hc+bc1) @ wc2 + bc2)
    float part[EE] = {};
    for (int j2 = tid; j2 < HH; j2 += 256) {
      float v = fmaxf(hc_raw[b * HH + j2] + bc1[j2], 0.f);
      for (int e = 0; e < EE; ++e) part[e] += v * wc2[j2 * EE + e];
    }
    for (int m = 1; m < 64; m <<= 1)
      for (int e = 0; e < EE; ++e) part[e] += __shfl_xor(part[e], m);
    int wave = tid >> 6, lane = tid & 63;
    if (lane == 0)
      for (int e = 0; e < EE; ++e) red[wave][e] = part[e];
    __syncthreads();
    if (tid < EE) {
      float s = bc2[tid];
      for (int w = 0; w < 4; ++w) s += red[w][tid];
      adj[b * EE + tid] = tanhf(s);
    }
    return;
  }

  // ---- GEMM blocks ----
  int m0 = blockIdx.x * BM, n0 = blockIdx.y * BN;
  if (tid < BN) b1s[tid] = b1[n0 + tid];

  int bid = blockIdx.y * gridDim.x + blockIdx.x;   // 0..511
  f32x4* zp = zout + (size_t)bid * ZF4_PER_BLOCK;
  const f32x4 z4 = {0.f, 0.f, 0.f, 0.f};

  int lane = tid & 63, wave = tid >> 6;
  int wm = wave & 1, wn = wave >> 1;   // wave tile: 64 rows x 32 cols
  int q = lane >> 4, mr = lane & 15;
  int lr = lane >> 2, lq = lane & 3;   // staging: row-within-group, 16B quarter

  f32x4 acc[4][2] = {};

  const unsigned short* Ag[3] = {Xh, Xm, Xl};
  const unsigned short* Bg[3] = {Wh, Wm, Wl};

  for (int k0 = 0; k0 < HH; k0 += BK) {
    __syncthreads();
#pragma unroll
    for (int j = 0; j < 6; ++j) {
      int i = wave + 4 * j;
      int s = i >> 3, g = i & 7;
      const unsigned short* gp =
          Ag[s] + (size_t)(m0 + g * 16 + lr) * HH + k0 + lq * 8;
      gload_lds16(gp, &As[s][g * 512]);
    }
#pragma unroll
    for (int j = 0; j < 3; ++j) {
      int i = wave + 4 * j;
      int s = i >> 2, g = i & 3;
      const unsigned short* gp =
          Bg[s] + (size_t)(n0 + g * 16 + lr) * HH + k0 + lq * 8;
      gload_lds16(gp, &Bs[s][g * 512]);
    }
    __syncthreads();

    // zero-fill slice: NT stores at top of compute phase, drain behind MFMA
    {
      int ki = k0 >> 5;
      f32x4* zb = zp + ki * (256 * 6) + tid;
#pragma unroll
      for (int j = 0; j < 6; ++j) __builtin_nontemporal_store(z4, &zb[j * 256]);
    }

    short8 af[3][4], bf[3][2];
#pragma unroll
    for (int s = 0; s < 3; ++s) {
#pragma unroll
      for (int mi = 0; mi < 4; ++mi)
        af[s][mi] = *(const short8*)&As[s][(wm * 64 + mi * 16 + mr) * BK + q * 8];
#pragma unroll
      for (int ni = 0; ni < 2; ++ni)
        bf[s][ni] = *(const short8*)&Bs[s][(wn * 32 + ni * 16 + mr) * BK + q * 8];
    }
#pragma unroll
    for (int mi = 0; mi < 4; ++mi)
#pragma unroll
      for (int ni = 0; ni < 2; ++ni) {
        f32x4 c = acc[mi][ni];
        c = __builtin_amdgcn_mfma_f32_16x16x32_bf16(af[0][mi], bf[0][ni], c, 0, 0, 0); // h.h
        c = __builtin_amdgcn_mfma_f32_16x16x32_bf16(af[0][mi], bf[1][ni], c, 0, 0, 0); // h.m
        c = __builtin_amdgcn_mfma_f32_16x16x32_bf16(af[1][mi], bf[0][ni], c, 0, 0, 0); // m.h
        c = __builtin_amdgcn_mfma_f32_16x16x32_bf16(af[0][mi], bf[2][ni], c, 0, 0, 0); // h.l
        c = __builtin_amdgcn_mfma_f32_16x16x32_bf16(af[2][mi], bf[0][ni], c, 0, 0, 0); // l.h
        c = __builtin_amdgcn_mfma_f32_16x16x32_bf16(af[1][mi], bf[1][ni], c, 0, 0, 0); // m.m
        acc[mi][ni] = c;
      }
  }

  // epilogue: relu(+b1) -> store h fp32 (C layout: col=lane&15, row=q*4+r)
#pragma unroll
  for (int ni = 0; ni < 2; ++ni) {
    int cloc = wn * 32 + ni * 16 + mr;
    int col = n0 + cloc;
    float bv = b1s[cloc];
#pragma unroll
    for (int mi = 0; mi < 4; ++mi)
#pragma unroll
      for (int r = 0; r < 4; ++r) {
        int row = m0 + wm * 64 + mi * 16 + q * 4 + r;
        hbuf[(size_t)row * HH + col] = fmaxf(acc[mi][ni][r] + bv, 0.f);
      }
  }
}

// ---------------- D3: logits + softmax + top2 + psum + fused route ----------
// Last-arrival block (device-scope counter) runs the serial route inline,
// removing the separate k_route launch. Route LDS aliases w2s.
__global__ __launch_bounds__(256) void k_logits(
    const float* __restrict__ h, const float* __restrict__ w2,
    const float* __restrict__ b2, const float* __restrict__ adj,
    float* __restrict__ probs_out, int* __restrict__ idx_pack,
    float* __restrict__ p1o, float* __restrict__ p2o, float* __restrict__ psum,
    int* __restrict__ ctr,
    float* __restrict__ disp, float* __restrict__ comb, float* __restrict__ aux_out) {
  __shared__ float w2s[HH * EE];   // 32KB
  __shared__ float ps[EE];
  __shared__ int tot[EE];
  __shared__ int sflag;
  int tid = threadIdx.x;
#pragma unroll
  for (int j = 0; j < 8; ++j)
    ((float4*)w2s)[tid + 256 * j] = ((const float4*)w2)[tid + 256 * j];
  if (tid < EE) ps[tid] = 0.f;
  __syncthreads();

  int lane = tid & 63, wave = tid >> 6;
  int t = blockIdx.x * 4 + wave;
  float acc[EE] = {};
  const float* hr = h + (size_t)t * HH;
#pragma unroll
  for (int i = 0; i < 16; ++i) {
    int e = lane + 64 * i;
    float hv = hr[e];
    float4 wa = ((const float4*)w2s)[2 * e];
    float4 wb = ((const float4*)w2s)[2 * e + 1];
    acc[0] += hv * wa.x; acc[1] += hv * wa.y; acc[2] += hv * wa.z; acc[3] += hv * wa.w;
    acc[4] += hv * wb.x; acc[5] += hv * wb.y; acc[6] += hv * wb.z; acc[7] += hv * wb.w;
  }
#pragma unroll
  for (int m = 1; m < 64; m <<= 1)
#pragma unroll
    for (int e = 0; e < EE; ++e) acc[e] += __shfl_xor(acc[e], m);

  if (lane == 0) {
    int b = t >> 11;
    float l[EE];
    float mx = -1e30f;
    for (int e = 0; e < EE; ++e) {
      l[e] = acc[e] + b2[e] + adj[b * EE + e];
      mx = fmaxf(mx, l[e]);
    }
    float s = 0.f;
    for (int e = 0; e < EE; ++e) { l[e] = expf(l[e] - mx); s += l[e]; }
    float inv = 1.f / s;
    for (int e = 0; e < EE; ++e) { l[e] *= inv; probs_out[t * EE + e] = l[e]; }
    int e1 = 0; float p1 = l[0];
    for (int e = 1; e < EE; ++e) if (l[e] > p1) { p1 = l[e]; e1 = e; }
    int e2 = -1; float p2 = -1.f;
    for (int e = 0; e < EE; ++e) if (e != e1 && l[e] > p2) { p2 = l[e]; e2 = e; }
    float norm = 1.f / (p1 + p2 + 1e-8f);
    idx_pack[t] = e1 | (e2 << 8);
    p1o[t] = p1 * norm;
    p2o[t] = p2 * norm;
    for (int e = 0; e < EE; ++e) atomicAdd(&ps[e], l[e]);
  }
  __syncthreads();
  if (tid < EE) atomicAdd(&psum[tid], ps[tid]);

  // publish + last-arrival election
  __threadfence();
  __syncthreads();
  if (tid == 0) sflag = (atomicAdd(ctr, 1) == (int)gridDim.x - 1);
  __syncthreads();
  if (!sflag) return;
  __threadfence();

  // ---- route (last block only): serial-order capacity + scatter + aux ----
  int* cnt = (int*)w2s;   // 256*8 ints = 8KB alias (w2s no longer needed)
  const int CH = NASSIGN / 256;
  int n0 = tid * CH;
  int local[EE] = {};
  for (int n = n0; n < n0 + CH; ++n) {
    int tt = n >> 1;
    int pk = idx_pack[tt];
    int e = (n & 1) ? (pk >> 8) : (pk & 0xff);
    local[e]++;
  }
  for (int e = 0; e < EE; ++e) cnt[tid * EE + e] = local[e];
  __syncthreads();
  if (tid < EE) {
    int run = 0;
    for (int tt = 0; tt < 256; ++tt) { int v = cnt[tt * EE + tid]; cnt[tt * EE + tid] = run; run += v; }
    tot[tid] = run;
  }
  __syncthreads();
  int off[EE];
  for (int e = 0; e < EE; ++e) off[e] = cnt[tid * EE + e];
  for (int n = n0; n < n0 + CH; ++n) {
    int tt = n >> 1;
    int pk = idx_pack[tt];
    int e; float p;
    if (n & 1) { e = pk >> 8; p = p2o[tt]; } else { e = pk & 0xff; p = p1o[tt]; }
    int pos = off[e]++;
    if (pos < CAP) {
      size_t o = (size_t)tt * EE * CAP + (size_t)e * CAP + pos;
      disp[o] = 1.0f;
      comb[o] = p;
    }
  }
  if (tid == 0) {
    float aux = 0.f;
    for (int e = 0; e < EE; ++e)
      aux += (psum[e] / (float)NTOK) * ((float)tot[e] / (float)NASSIGN);
    aux_out[0] = aux * (float)EE;
  }
}

// ---------------- fallback path kernels (fp32, unchanged) ----------------
__global__ void k_avgp(const float* __restrict__ x, float* __restrict__ avg_part) {
  int h = blockIdx.x * 256 + threadIdx.x;
  int c = blockIdx.y;
  int b = blockIdx.z;
  const float* p = x + (size_t)b * SS * HH + (size_t)(c * 128) * HH + h;
  float s = 0.f;
  for (int i = 0; i < 128; ++i) s += p[(size_t)i * HH];
  avg_part[(c * BB + b) * HH + h] = s;
}

__global__ void k_hc(const float* __restrict__ avg_part, const float* __restrict__ chr,
                     const float* __restrict__ wc1, float* __restrict__ hc_raw) {
  __shared__ float avg_s[128];
  int tid = threadIdx.x;
  int j = blockIdx.x * 256 + tid;
  int c = blockIdx.y;
  int b = blockIdx.z;
  if (tid < 128) {
    float s = 0.f;
    for (int cc = 0; cc < 16; ++cc)
      s += avg_part[(cc * BB + b) * HH + c * 128 + tid];
    avg_s[tid] = s * (1.0f / SS);
  }
  __syncthreads();
  float acc = 0.f;
  for (int il = 0; il < 128; ++il)
    acc += avg_s[il] * wc1[(size_t)(c * 128 + il) * HH + j];
  if (c == 7)
    for (int i = 0; i < EE; ++i)
      acc += chr[i] * wc1[(size_t)(HH + i) * HH + j];
  atomicAdd(&hc_raw[b * HH + j], acc);
}

__global__ void k_adj(const float* __restrict__ hc_raw, const float* __restrict__ bc1,
                      const float* __restrict__ wc2, const float* __restrict__ bc2,
                      float* __restrict__ adj) {
  int b = blockIdx.x;
  int tid = threadIdx.x;
  float part[EE] = {};
  for (int j = tid; j < HH; j += 256) {
    float v = fmaxf(hc_raw[b * HH + j] + bc1[j], 0.f);
    for (int e = 0; e < EE; ++e) part[e] += v * wc2[j * EE + e];
  }
  for (int m = 1; m < 64; m <<= 1)
    for (int e = 0; e < EE; ++e) part[e] += __shfl_xor(part[e], m);
  __shared__ float red[4][EE];
  int wave = tid >> 6, lane = tid & 63;
  if (lane == 0)
    for (int e = 0; e < EE; ++e) red[wave][e] = part[e];
  __syncthreads();
  if (tid < EE) {
    float s = bc2[tid];
    for (int w = 0; w < 4; ++w) s += red[w][tid];
    adj[b * EE + tid] = tanhf(s);
  }
}

__global__ __launch_bounds__(256) void k_gemm_f32(
    const float* __restrict__ X, const float* __restrict__ w1,
    const float* __restrict__ b1, const float* __restrict__ w2,
    float* __restrict__ logits) {
  __shared__ float Asf[16][65];
  __shared__ float Bsf[16][64];
  __shared__ float w2sf[64][EE];
  int tid = threadIdx.x;
  int m0 = blockIdx.x * 64, n0 = blockIdx.y * 64;
  for (int i = tid; i < 64 * EE; i += 256)
    w2sf[i / EE][i % EE] = w2[(size_t)(n0 + i / EE) * EE + (i % EE)];
  float acc[4][4] = {};
  int tx = tid & 15, ty = tid >> 4;
  for (int k0 = 0; k0 < HH; k0 += 16) {
    for (int idx = tid; idx < 64 * 16; idx += 256) {
      int m = idx >> 4, kk = idx & 15;
      Asf[kk][m] = X[(size_t)(m0 + m) * HH + k0 + kk];
    }
    for (int idx = tid; idx < 16 * 64; idx += 256) {
      int kk = idx >> 6, n = idx & 63;
      Bsf[kk][n] = w1[(size_t)(k0 + kk) * HH + n0 + n];
    }
    __syncthreads();
    for (int kk = 0; kk < 16; ++kk) {
      float a[4], bb[4];
      for (int i = 0; i < 4; ++i) a[i] = Asf[kk][ty * 4 + i];
      for (int j = 0; j < 4; ++j) bb[j] = Bsf[kk][tx * 4 + j];
      for (int i = 0; i < 4; ++i)
        for (int j = 0; j < 4; ++j) acc[i][j] += a[i] * bb[j];
    }
    __syncthreads();
  }
  float p[4][EE] = {};
  for (int i = 0; i < 4; ++i)
    for (int j = 0; j < 4; ++j) {
      int c = tx * 4 + j;
      float v = fmaxf(acc[i][j] + b1[n0 + c], 0.f);
      for (int e = 0; e < EE; ++e) p[i][e] += v * w2sf[c][e];
    }
  for (int m = 1; m < 16; m <<= 1)
    for (int i = 0; i < 4; ++i)
      for (int e = 0; e < EE; ++e) p[i][e] += __shfl_xor(p[i][e], m);
  if (tx == 0)
    for (int i = 0; i < 4; ++i)
      for (int e = 0; e < EE; ++e)
        atomicAdd(&logits[(size_t)(m0 + ty * 4 + i) * EE + e], p[i][e]);
}

__global__ void k_init_logits(const float* __restrict__ adj, const float* __restrict__ b2,
                              float* __restrict__ logits) {
  int i = blockIdx.x * 256 + threadIdx.x;
  int e = i & 7;
  int t = i >> 3;
  int b = t >> 11;
  logits[i] = b2[e] + adj[b * EE + e];
}

__global__ void k_softmax(const float* __restrict__ logits, float* __restrict__ probs_out,
                          int* __restrict__ idx_pack, float* __restrict__ p1o,
                          float* __restrict__ p2o, float* __restrict__ psum) {
  int t = blockIdx.x * 256 + threadIdx.x;
  float l[EE];
  float mx = -1e30f;
  for (int e = 0; e < EE; ++e) { l[e] = logits[t * EE + e]; mx = fmaxf(mx, l[e]); }
  float s = 0.f;
  for (int e = 0; e < EE; ++e) { l[e] = expf(l[e] - mx); s += l[e]; }
  float inv = 1.f / s;
  for (int e = 0; e < EE; ++e) { l[e] *= inv; probs_out[t * EE + e] = l[e]; }
  int e1 = 0; float p1 = l[0];
  for (int e = 1; e < EE; ++e) if (l[e] > p1) { p1 = l[e]; e1 = e; }
  int e2 = -1; float p2 = -1.f;
  for (int e = 0; e < EE; ++e) if (e != e1 && l[e] > p2) { p2 = l[e]; e2 = e; }
  float norm = 1.f / (p1 + p2 + 1e-8f);
  idx_pack[t] = e1 | (e2 << 8);
  p1o[t] = p1 * norm;
  p2o[t] = p2 * norm;
  for (int m = 1; m < 64; m <<= 1)
    for (int e = 0; e < EE; ++e) l[e] += __shfl_xor(l[e], m);
  if ((threadIdx.x & 63) == 0)
    for (int e = 0; e < EE; ++e) atomicAdd(&psum[e], l[e]);
}

__global__ __launch_bounds__(256) void k_route(
    const int* __restrict__ idx_pack, const float* __restrict__ p1,
    const float* __restrict__ p2, const float* __restrict__ psum,
    float* __restrict__ disp, float* __restrict__ comb, float* __restrict__ aux_out) {
  __shared__ int cnt[256][EE];
  __shared__ int tot[EE];
  int tid = threadIdx.x;
  const int CH = NASSIGN / 256;
  int n0 = tid * CH;
  int local[EE] = {};
  for (int n = n0; n < n0 + CH; ++n) {
    int t = n >> 1;
    int pk = idx_pack[t];
    int e = (n & 1) ? (pk >> 8) : (pk & 0xff);
    local[e]++;
  }
  for (int e = 0; e < EE; ++e) cnt[tid][e] = local[e];
  __syncthreads();
  if (tid < EE) {
    int run = 0;
    for (int t = 0; t < 256; ++t) { int v = cnt[t][tid]; cnt[t][tid] = run; run += v; }
    tot[tid] = run;
  }
  __syncthreads();
  int off[EE];
  for (int e = 0; e < EE; ++e) off[e] = cnt[tid][e];
  for (int n = n0; n < n0 + CH; ++n) {
    int t = n >> 1;
    int pk = idx_pack[t];
    int e; float p;
    if (n & 1) { e = pk >> 8; p = p2[t]; } else { e = pk & 0xff; p = p1[t]; }
    int pos = off[e]++;
    if (pos < CAP) {
      size_t o = (size_t)t * EE * CAP + (size_t)e * CAP + pos;
      disp[o] = 1.0f;
      comb[o] = p;
    }
  }
  if (tid == 0) {
    float aux = 0.f;
    for (int e = 0; e < EE; ++e)
      aux += (psum[e] / (float)NTOK) * ((float)tot[e] / (float)NASSIGN);
    aux_out[0] = aux * (float)EE;
  }
}

extern "C" void kernel_launch(void* const* d_in, const int* in_sizes, int n_in,
                              void* d_out, int out_size, void* d_ws, size_t ws_size,
                              hipStream_t stream) {
  const float* x   = (const float*)d_in[0];
  const float* w1  = (const float*)d_in[1];
  const float* b1  = (const float*)d_in[2];
  const float* w2  = (const float*)d_in[3];
  const float* b2  = (const float*)d_in[4];
  const float* wc1 = (const float*)d_in[5];
  const float* bc1 = (const float*)d_in[6];
  const float* wc2 = (const float*)d_in[7];
  const float* bc2 = (const float*)d_in[8];
  const float* chr = (const float*)d_in[9];

  float* out = (float*)d_out;
  float* disp  = out;
  float* comb  = disp + (size_t)NTOK * EE * CAP;
  float* probs = comb + (size_t)NTOK * EE * CAP;
  float* aux   = probs + (size_t)NTOK * EE;

  float* ws = (float*)d_ws;
  float* psum   = ws + WS_PSUM;
  int*   ctr    = (int*)(ws + WS_CTR);
  float* hcr    = ws + WS_HC;
  float* adj    = ws + WS_ADJ;
  float* p1     = ws + WS_P1;
  float* p2     = ws + WS_P2;
  int*   idxp   = (int*)(ws + WS_IDX);
  float* logits = ws + WS_LOGITS;           // fallback only
  float* avgp   = ws + WS_LOGITS;           // avg partials

  char* wsb = (char*)d_ws;
  unsigned short* Xh = (unsigned short*)(wsb + WS_BF16_BYTE);
  unsigned short* Xm = Xh + (size_t)NTOK * HH;
  unsigned short* Xl = Xm + (size_t)NTOK * HH;
  unsigned short* Wh = Xl + (size_t)NTOK * HH;
  unsigned short* Wm = Wh + (size_t)HH * HH;
  unsigned short* Wl = Wm + (size_t)HH * HH;
  float* hbuf = (float*)(wsb + WS_H_BYTE);

  bool use_mfma = ws_size >= WS_NEED;

  if (use_mfma) {
    // D1: prep_x + prep_w + avg partials + ws-head zero (incl counters)
    k_prep<<<PREPX_BLKS + PREPW_BLKS + AVG_BLKS, 256, 0, stream>>>(
        x, w1, Xh, Xm, Xl, Wh, Wm, Wl, ws, avgp);
    // D2: 512 GEMM blocks (NT zeroing of disp/comb) + 32 hc blocks (+adj)
    k_gemm_mfma<<<dim3(NTOK / BM, HH / BN + 1), 256, 0, stream>>>(
        Xh, Xm, Xl, Wh, Wm, Wl, b1, hbuf, (f32x4*)d_out,
        avgp, chr, wc1, bc1, wc2, bc2, hcr, adj, ctr);
    // D3: logits + softmax + top2 + psum + fused route (last block)
    k_logits<<<NTOK / 4, 256, 0, stream>>>(hbuf, w2, b2, adj, probs, idxp, p1, p2,
                                           psum, ctr + 2, disp, comb, aux);
  } else {
    hipMemsetAsync(d_ws, 0, WS_ZERO_BYTES, stream);
    hipMemsetAsync(d_out, 0, (size_t)out_size * sizeof(float), stream);
    k_avgp<<<dim3(HH / 256, 16, BB), 256, 0, stream>>>(x, avgp);
    k_hc<<<dim3(HH / 256, 8, BB), 256, 0, stream>>>(avgp, chr, wc1, hcr);
    k_adj<<<BB, 256, 0, stream>>>(hcr, bc1, wc2, bc2, adj);
    k_init_logits<<<(NTOK * EE) / 256, 256, 0, stream>>>(adj, b2, logits);
    k_gemm_f32<<<dim3(NTOK / 64, HH / 64), 256, 0, stream>>>(x, w1, b1, w2, logits);
    k_softmax<<<NTOK / 256, 256, 0, stream>>>(logits, probs, idxp, p1, p2, psum);
    k_route<<<1, 256, 0, stream>>>(idxp, p1, p2, psum, disp, comb, aux);
  }
}

// Round 9
// 507.324 us; speedup vs baseline: 1.1957x; 1.1957x over previous
//
#include <hip/hip_runtime.h>
#include <hip/hip_bf16.h>

#define BB 2
#define SS 2048
#define HH 1024
#define EE 8
#define KK 2
#define CAP 1536
#define NTOK (BB * SS)        // 4096
#define NASSIGN (NTOK * KK)   // 8192

// ---------------- workspace layout (float indices) ----------------
#define WS_PSUM   0            // 8
#define WS_AVG    8            // 2048  (fallback path full sums; unused in mfma path)
#define WS_HC     2056         // 2048  (raw pre-bias pre-relu, atomic target)
#define WS_ADJ    4104         // 16
#define WS_P1     4120         // 4096
#define WS_P2     8216         // 4096
#define WS_IDX    12312        // 4096 ints
#define WS_LOGITS 16408        // 32768: fallback logits OR avg partials (16*2*1024)
#define WS_ZERO_FLOATS 4112    // psum+avg+hc head (zeroed by prep blk0 / memset)
#define WS_ZERO_BYTES 16448
#define WS_BF16_BYTE 196704    // bf16 planes start here (16B aligned)
// planes: Xh/Xm/Xl 3*8388608 B + Wh/Wm/Wl 3*2097152 B = 31457280 B
#define WS_H_BYTE (WS_BF16_BYTE + 31457280)   // h fp32: 16777216 B
#define WS_NEED (WS_H_BYTE + 16777216ull)

using short8 = __attribute__((ext_vector_type(8))) short;
using u16x8  = __attribute__((ext_vector_type(8))) unsigned short;
using f32x4  = __attribute__((ext_vector_type(4))) float;

// ---- bf16 split helpers (manual RNE) ----
__device__ __forceinline__ unsigned short f2bf(float f) {
  unsigned u = __float_as_uint(f);
  unsigned r = (u + 0x7fffu + ((u >> 16) & 1u)) >> 16;
  return (unsigned short)r;
}
__device__ __forceinline__ float bf2f(unsigned short h) {
  return __uint_as_float((unsigned)h << 16);
}
__device__ __forceinline__ void split3(float x, unsigned short& h,
                                       unsigned short& m, unsigned short& l) {
  h = f2bf(x);
  float r = x - bf2f(h);
  m = f2bf(r);
  l = f2bf(r - bf2f(m));
}

// async global->LDS, 16B per lane; lptr is wave-uniform base, HW adds lane*16
__device__ __forceinline__ void gload_lds16(const void* g, void* l) {
  __builtin_amdgcn_global_load_lds(
      (const __attribute__((address_space(1))) void*)g,
      (__attribute__((address_space(3))) void*)l, 16, 0, 0);
}

// ---------------- D1: consolidated prep dispatch ----------------
// blocks [0,4096): split X -> bf16 planes (blk0 also zeros ws scalar head)
// blocks [4096,4352): split+transpose w1 -> bf16 planes
// blocks [4352,4480): avg partial sums (no atomics, no zero-init needed)
#define PREPX_BLKS 4096
#define PREPW_BLKS 256
#define AVG_BLKS   128
__global__ __launch_bounds__(256) void k_prep(
    const float* __restrict__ x, const float* __restrict__ w1,
    unsigned short* __restrict__ Xh, unsigned short* __restrict__ Xm,
    unsigned short* __restrict__ Xl,
    unsigned short* __restrict__ Wh, unsigned short* __restrict__ Wm,
    unsigned short* __restrict__ Wl,
    float* __restrict__ wshead, float* __restrict__ avg_part) {
  __shared__ unsigned short Th[64 * 65], Tm[64 * 65], Tl[64 * 65];
  int tid = threadIdx.x;
  int bid = blockIdx.x;
  if (bid < PREPX_BLKS) {
    if (bid == 0)
      for (int j = tid; j < WS_ZERO_FLOATS; j += 256) wshead[j] = 0.f;
    int i = (bid * 256 + tid) * 4;
    float4 v = *(const float4*)&x[i];
    unsigned short h[4], m[4], l[4];
    split3(v.x, h[0], m[0], l[0]);
    split3(v.y, h[1], m[1], l[1]);
    split3(v.z, h[2], m[2], l[2]);
    split3(v.w, h[3], m[3], l[3]);
    *(ushort4*)&Xh[i] = make_ushort4(h[0], h[1], h[2], h[3]);
    *(ushort4*)&Xm[i] = make_ushort4(m[0], m[1], m[2], m[3]);
    *(ushort4*)&Xl[i] = make_ushort4(l[0], l[1], l[2], l[3]);
  } else if (bid < PREPX_BLKS + PREPW_BLKS) {
    int pid = bid - PREPX_BLKS;
    int k0 = (pid & 15) * 64, n0 = (pid >> 4) * 64;
    for (int i = 0; i < 16; ++i) {
      int e = i * 256 + tid;
      int k = e >> 6, n = e & 63;
      float v = w1[(size_t)(k0 + k) * HH + n0 + n];
      unsigned short h, m, l;
      split3(v, h, m, l);
      Th[n * 65 + k] = h; Tm[n * 65 + k] = m; Tl[n * 65 + k] = l;
    }
    __syncthreads();
    for (int i = 0; i < 16; ++i) {
      int e = i * 256 + tid;
      int n = e >> 6, k = e & 63;
      size_t o = (size_t)(n0 + n) * HH + k0 + k;
      Wh[o] = Th[n * 65 + k]; Wm[o] = Tm[n * 65 + k]; Wl[o] = Tl[n * 65 + k];
    }
  } else {
    int pid = bid - PREPX_BLKS - PREPW_BLKS;  // 0..127
    int h = (pid & 3) * 256 + tid;
    int c = (pid >> 2) & 15;
    int b = pid >> 6;
    const float* p = x + (size_t)b * SS * HH + (size_t)(c * 128) * HH + h;
    float s = 0.f;
    for (int i = 0; i < 128; ++i) s += p[(size_t)i * HH];
    avg_part[(c * BB + b) * HH + h] = s;   // raw partial sum
  }
}

// standalone avg-partials kernel (fallback path only)
__global__ void k_avgp(const float* __restrict__ x, float* __restrict__ avg_part) {
  int h = blockIdx.x * 256 + threadIdx.x;
  int c = blockIdx.y;
  int b = blockIdx.z;
  const float* p = x + (size_t)b * SS * HH + (size_t)(c * 128) * HH + h;
  float s = 0.f;
  for (int i = 0; i < 128; ++i) s += p[(size_t)i * HH];
  avg_part[(c * BB + b) * HH + h] = s;
}

// hc_raw += partial dot over i-chunk; reduces the 16 avg partials through LDS
__global__ void k_hc(const float* __restrict__ avg_part, const float* __restrict__ chr,
                     const float* __restrict__ wc1, float* __restrict__ hc_raw) {
  __shared__ float avg_s[128];
  int tid = threadIdx.x;
  int j = blockIdx.x * 256 + tid;
  int c = blockIdx.y;
  int b = blockIdx.z;
  if (tid < 128) {
    float s = 0.f;
    for (int cc = 0; cc < 16; ++cc)
      s += avg_part[(cc * BB + b) * HH + c * 128 + tid];
    avg_s[tid] = s * (1.0f / SS);
  }
  __syncthreads();
  float acc = 0.f;
  for (int il = 0; il < 128; ++il)
    acc += avg_s[il] * wc1[(size_t)(c * 128 + il) * HH + j];
  if (c == 7)
    for (int i = 0; i < EE; ++i)
      acc += chr[i] * wc1[(size_t)(HH + i) * HH + j];
  atomicAdd(&hc_raw[b * HH + j], acc);
}

// standalone adj kernel (fallback path only; mfma path runs adj inside D3)
__global__ void k_adj(const float* __restrict__ hc_raw, const float* __restrict__ bc1,
                      const float* __restrict__ wc2, const float* __restrict__ bc2,
                      float* __restrict__ adj) {
  int b = blockIdx.x;
  int tid = threadIdx.x;
  float part[EE] = {};
  for (int j = tid; j < HH; j += 256) {
    float v = fmaxf(hc_raw[b * HH + j] + bc1[j], 0.f);
    for (int e = 0; e < EE; ++e) part[e] += v * wc2[j * EE + e];
  }
  for (int m = 1; m < 64; m <<= 1)
    for (int e = 0; e < EE; ++e) part[e] += __shfl_xor(part[e], m);
  __shared__ float red[4][EE];
  int wave = tid >> 6, lane = tid & 63;
  if (lane == 0)
    for (int e = 0; e < EE; ++e) red[wave][e] = part[e];
  __syncthreads();
  if (tid < EE) {
    float s = bc2[tid];
    for (int w = 0; w < 4; ++w) s += red[w][tid];
    adj[b * EE + tid] = tanhf(s);
  }
}

// ---------------- D3: MFMA split-bf16 GEMM + output zeroing + adj ----------
// Grid (32,17): y<16 -> GEMM blocks, each zero-fills a 786KB slice of
// disp/comb via NT stores issued in the compute phase (R5 structure: stores
// drain behind MFMA; NT avoids evicting the bf16 planes from L2/L3).
// y==16, x<2 -> adj blocks (depend on hc_raw from D2; consumed by D4).
#define BM 128
#define BN 64
#define BK 32
#define ZF4_PER_BLOCK 49152   // 25165824 f4 / 512 gemm blocks
__global__ __launch_bounds__(256) void k_gemm_mfma(
    const unsigned short* __restrict__ Xh, const unsigned short* __restrict__ Xm,
    const unsigned short* __restrict__ Xl,
    const unsigned short* __restrict__ Wh, const unsigned short* __restrict__ Wm,
    const unsigned short* __restrict__ Wl,
    const float* __restrict__ b1, float* __restrict__ hbuf,
    f32x4* __restrict__ zout,
    const float* __restrict__ hc_raw, const float* __restrict__ bc1,
    const float* __restrict__ wc2, const float* __restrict__ bc2,
    float* __restrict__ adj) {
  __shared__ unsigned short As[3][BM * BK];   // 3 x 8KB
  __shared__ unsigned short Bs[3][BN * BK];   // 3 x 4KB
  __shared__ float b1s[BN];
  __shared__ float red[4][EE];
  int tid = threadIdx.x;

  if (blockIdx.y == HH / BN) {   // adj blocks
    if (blockIdx.x >= BB) return;
    int b = blockIdx.x;
    float part[EE] = {};
    for (int j = tid; j < HH; j += 256) {
      float v = fmaxf(hc_raw[b * HH + j] + bc1[j], 0.f);
      for (int e = 0; e < EE; ++e) part[e] += v * wc2[j * EE + e];
    }
    for (int m = 1; m < 64; m <<= 1)
      for (int e = 0; e < EE; ++e) part[e] += __shfl_xor(part[e], m);
    int wave = tid >> 6, lane = tid & 63;
    if (lane == 0)
      for (int e = 0; e < EE; ++e) red[wave][e] = part[e];
    __syncthreads();
    if (tid < EE) {
      float s = bc2[tid];
      for (int w = 0; w < 4; ++w) s += red[w][tid];
      adj[b * EE + tid] = tanhf(s);
    }
    return;
  }

  int m0 = blockIdx.x * BM, n0 = blockIdx.y * BN;
  if (tid < BN) b1s[tid] = b1[n0 + tid];

  int bid = blockIdx.y * gridDim.x + blockIdx.x;   // 0..511
  f32x4* zp = zout + (size_t)bid * ZF4_PER_BLOCK;
  const f32x4 z4 = {0.f, 0.f, 0.f, 0.f};

  int lane = tid & 63, wave = tid >> 6;
  int wm = wave & 1, wn = wave >> 1;   // wave tile: 64 rows x 32 cols
  int q = lane >> 4, mr = lane & 15;
  int lr = lane >> 2, lq = lane & 3;   // staging: row-within-group, 16B quarter

  f32x4 acc[4][2] = {};

  const unsigned short* Ag[3] = {Xh, Xm, Xl};
  const unsigned short* Bg[3] = {Wh, Wm, Wl};

  for (int k0 = 0; k0 < HH; k0 += BK) {
    __syncthreads();
    // A: 24 wave-instrs (3 planes x 8 groups of 16 rows); this wave does 6
#pragma unroll
    for (int j = 0; j < 6; ++j) {
      int i = wave + 4 * j;
      int s = i >> 3, g = i & 7;
      const unsigned short* gp =
          Ag[s] + (size_t)(m0 + g * 16 + lr) * HH + k0 + lq * 8;
      gload_lds16(gp, &As[s][g * 512]);
    }
    // B: 12 wave-instrs (3 planes x 4 groups of 16 rows); this wave does 3
#pragma unroll
    for (int j = 0; j < 3; ++j) {
      int i = wave + 4 * j;
      int s = i >> 2, g = i & 3;
      const unsigned short* gp =
          Bg[s] + (size_t)(n0 + g * 16 + lr) * HH + k0 + lq * 8;
      gload_lds16(gp, &Bs[s][g * 512]);
    }
    __syncthreads();

    // zero-fill slice: NT stores issued at the top of the compute phase,
    // drain during MFMA; NT keeps the bf16 planes resident in L2/L3.
    {
      int ki = k0 >> 5;
      f32x4* zb = zp + ki * (256 * 6) + tid;
#pragma unroll
      for (int j = 0; j < 6; ++j) __builtin_nontemporal_store(z4, &zb[j * 256]);
    }

    short8 af[3][4], bf[3][2];
#pragma unroll
    for (int s = 0; s < 3; ++s) {
#pragma unroll
      for (int mi = 0; mi < 4; ++mi)
        af[s][mi] = *(const short8*)&As[s][(wm * 64 + mi * 16 + mr) * BK + q * 8];
#pragma unroll
      for (int ni = 0; ni < 2; ++ni)
        bf[s][ni] = *(const short8*)&Bs[s][(wn * 32 + ni * 16 + mr) * BK + q * 8];
    }
#pragma unroll
    for (int mi = 0; mi < 4; ++mi)
#pragma unroll
      for (int ni = 0; ni < 2; ++ni) {
        f32x4 c = acc[mi][ni];
        c = __builtin_amdgcn_mfma_f32_16x16x32_bf16(af[0][mi], bf[0][ni], c, 0, 0, 0); // h.h
        c = __builtin_amdgcn_mfma_f32_16x16x32_bf16(af[0][mi], bf[1][ni], c, 0, 0, 0); // h.m
        c = __builtin_amdgcn_mfma_f32_16x16x32_bf16(af[1][mi], bf[0][ni], c, 0, 0, 0); // m.h
        c = __builtin_amdgcn_mfma_f32_16x16x32_bf16(af[0][mi], bf[2][ni], c, 0, 0, 0); // h.l
        c = __builtin_amdgcn_mfma_f32_16x16x32_bf16(af[2][mi], bf[0][ni], c, 0, 0, 0); // l.h
        c = __builtin_amdgcn_mfma_f32_16x16x32_bf16(af[1][mi], bf[1][ni], c, 0, 0, 0); // m.m
        acc[mi][ni] = c;
      }
  }

  // epilogue: relu(+b1) -> store h fp32 (C layout: col=lane&15, row=q*4+r)
#pragma unroll
  for (int ni = 0; ni < 2; ++ni) {
    int cloc = wn * 32 + ni * 16 + mr;
    int col = n0 + cloc;
    float bv = b1s[cloc];
#pragma unroll
    for (int mi = 0; mi < 4; ++mi)
#pragma unroll
      for (int r = 0; r < 4; ++r) {
        int row = m0 + wm * 64 + mi * 16 + q * 4 + r;
        hbuf[(size_t)row * HH + col] = fmaxf(acc[mi][ni][r] + bv, 0.f);
      }
  }
}

// fused: logits = h@w2 + b2 + adj; softmax; top-2; psum  (one wave per token)
__global__ __launch_bounds__(256) void k_logits(
    const float* __restrict__ h, const float* __restrict__ w2,
    const float* __restrict__ b2, const float* __restrict__ adj,
    float* __restrict__ probs_out, int* __restrict__ idx_pack,
    float* __restrict__ p1o, float* __restrict__ p2o, float* __restrict__ psum) {
  __shared__ float w2s[HH * EE];   // 32KB
  __shared__ float ps[EE];
  int tid = threadIdx.x;
#pragma unroll
  for (int j = 0; j < 8; ++j)
    ((float4*)w2s)[tid + 256 * j] = ((const float4*)w2)[tid + 256 * j];
  if (tid < EE) ps[tid] = 0.f;
  __syncthreads();

  int lane = tid & 63, wave = tid >> 6;
  int t = blockIdx.x * 4 + wave;
  float acc[EE] = {};
  const float* hr = h + (size_t)t * HH;
#pragma unroll
  for (int i = 0; i < 16; ++i) {
    int e = lane + 64 * i;
    float hv = hr[e];
    float4 wa = ((const float4*)w2s)[2 * e];
    float4 wb = ((const float4*)w2s)[2 * e + 1];
    acc[0] += hv * wa.x; acc[1] += hv * wa.y; acc[2] += hv * wa.z; acc[3] += hv * wa.w;
    acc[4] += hv * wb.x; acc[5] += hv * wb.y; acc[6] += hv * wb.z; acc[7] += hv * wb.w;
  }
#pragma unroll
  for (int m = 1; m < 64; m <<= 1)
#pragma unroll
    for (int e = 0; e < EE; ++e) acc[e] += __shfl_xor(acc[e], m);

  if (lane == 0) {
    int b = t >> 11;
    float l[EE];
    float mx = -1e30f;
    for (int e = 0; e < EE; ++e) {
      l[e] = acc[e] + b2[e] + adj[b * EE + e];
      mx = fmaxf(mx, l[e]);
    }
    float s = 0.f;
    for (int e = 0; e < EE; ++e) { l[e] = expf(l[e] - mx); s += l[e]; }
    float inv = 1.f / s;
    for (int e = 0; e < EE; ++e) { l[e] *= inv; probs_out[t * EE + e] = l[e]; }
    int e1 = 0; float p1 = l[0];
    for (int e = 1; e < EE; ++e) if (l[e] > p1) { p1 = l[e]; e1 = e; }
    int e2 = -1; float p2 = -1.f;
    for (int e = 0; e < EE; ++e) if (e != e1 && l[e] > p2) { p2 = l[e]; e2 = e; }
    float norm = 1.f / (p1 + p2 + 1e-8f);
    idx_pack[t] = e1 | (e2 << 8);
    p1o[t] = p1 * norm;
    p2o[t] = p2 * norm;
    for (int e = 0; e < EE; ++e) atomicAdd(&ps[e], l[e]);
  }
  __syncthreads();
  if (tid < EE) atomicAdd(&psum[tid], ps[tid]);
}

// ---------------- fp32 fallback GEMM (+ old softmax path) ----------------
__global__ __launch_bounds__(256) void k_gemm_f32(
    const float* __restrict__ X, const float* __restrict__ w1,
    const float* __restrict__ b1, const float* __restrict__ w2,
    float* __restrict__ logits) {
  __shared__ float Asf[16][65];
  __shared__ float Bsf[16][64];
  __shared__ float w2sf[64][EE];
  int tid = threadIdx.x;
  int m0 = blockIdx.x * 64, n0 = blockIdx.y * 64;
  for (int i = tid; i < 64 * EE; i += 256)
    w2sf[i / EE][i % EE] = w2[(size_t)(n0 + i / EE) * EE + (i % EE)];
  float acc[4][4] = {};
  int tx = tid & 15, ty = tid >> 4;
  for (int k0 = 0; k0 < HH; k0 += 16) {
    for (int idx = tid; idx < 64 * 16; idx += 256) {
      int m = idx >> 4, kk = idx & 15;
      Asf[kk][m] = X[(size_t)(m0 + m) * HH + k0 + kk];
    }
    for (int idx = tid; idx < 16 * 64; idx += 256) {
      int kk = idx >> 6, n = idx & 63;
      Bsf[kk][n] = w1[(size_t)(k0 + kk) * HH + n0 + n];
    }
    __syncthreads();
    for (int kk = 0; kk < 16; ++kk) {
      float a[4], bb[4];
      for (int i = 0; i < 4; ++i) a[i] = Asf[kk][ty * 4 + i];
      for (int j = 0; j < 4; ++j) bb[j] = Bsf[kk][tx * 4 + j];
      for (int i = 0; i < 4; ++i)
        for (int j = 0; j < 4; ++j) acc[i][j] += a[i] * bb[j];
    }
    __syncthreads();
  }
  float p[4][EE] = {};
  for (int i = 0; i < 4; ++i)
    for (int j = 0; j < 4; ++j) {
      int c = tx * 4 + j;
      float v = fmaxf(acc[i][j] + b1[n0 + c], 0.f);
      for (int e = 0; e < EE; ++e) p[i][e] += v * w2sf[c][e];
    }
  for (int m = 1; m < 16; m <<= 1)
    for (int i = 0; i < 4; ++i)
      for (int e = 0; e < EE; ++e) p[i][e] += __shfl_xor(p[i][e], m);
  if (tx == 0)
    for (int i = 0; i < 4; ++i)
      for (int e = 0; e < EE; ++e)
        atomicAdd(&logits[(size_t)(m0 + ty * 4 + i) * EE + e], p[i][e]);
}

__global__ void k_init_logits(const float* __restrict__ adj, const float* __restrict__ b2,
                              float* __restrict__ logits) {
  int i = blockIdx.x * 256 + threadIdx.x;
  int e = i & 7;
  int t = i >> 3;
  int b = t >> 11;
  logits[i] = b2[e] + adj[b * EE + e];
}

__global__ void k_softmax(const float* __restrict__ logits, float* __restrict__ probs_out,
                          int* __restrict__ idx_pack, float* __restrict__ p1o,
                          float* __restrict__ p2o, float* __restrict__ psum) {
  int t = blockIdx.x * 256 + threadIdx.x;
  float l[EE];
  float mx = -1e30f;
  for (int e = 0; e < EE; ++e) { l[e] = logits[t * EE + e]; mx = fmaxf(mx, l[e]); }
  float s = 0.f;
  for (int e = 0; e < EE; ++e) { l[e] = expf(l[e] - mx); s += l[e]; }
  float inv = 1.f / s;
  for (int e = 0; e < EE; ++e) { l[e] *= inv; probs_out[t * EE + e] = l[e]; }
  int e1 = 0; float p1 = l[0];
  for (int e = 1; e < EE; ++e) if (l[e] > p1) { p1 = l[e]; e1 = e; }
  int e2 = -1; float p2 = -1.f;
  for (int e = 0; e < EE; ++e) if (e != e1 && l[e] > p2) { p2 = l[e]; e2 = e; }
  float norm = 1.f / (p1 + p2 + 1e-8f);
  idx_pack[t] = e1 | (e2 << 8);
  p1o[t] = p1 * norm;
  p2o[t] = p2 * norm;
  for (int m = 1; m < 64; m <<= 1)
    for (int e = 0; e < EE; ++e) l[e] += __shfl_xor(l[e], m);
  if ((threadIdx.x & 63) == 0)
    for (int e = 0; e < EE; ++e) atomicAdd(&psum[e], l[e]);
}

__global__ __launch_bounds__(256) void k_route(
    const int* __restrict__ idx_pack, const float* __restrict__ p1,
    const float* __restrict__ p2, const float* __restrict__ psum,
    float* __restrict__ disp, float* __restrict__ comb, float* __restrict__ aux_out) {
  __shared__ int cnt[256][EE];
  __shared__ int tot[EE];
  int tid = threadIdx.x;
  const int CH = NASSIGN / 256;
  int n0 = tid * CH;
  int local[EE] = {};
  for (int n = n0; n < n0 + CH; ++n) {
    int t = n >> 1;
    int pk = idx_pack[t];
    int e = (n & 1) ? (pk >> 8) : (pk & 0xff);
    local[e]++;
  }
  for (int e = 0; e < EE; ++e) cnt[tid][e] = local[e];
  __syncthreads();
  if (tid < EE) {
    int run = 0;
    for (int t = 0; t < 256; ++t) { int v = cnt[t][tid]; cnt[t][tid] = run; run += v; }
    tot[tid] = run;
  }
  __syncthreads();
  int off[EE];
  for (int e = 0; e < EE; ++e) off[e] = cnt[tid][e];
  for (int n = n0; n < n0 + CH; ++n) {
    int t = n >> 1;
    int pk = idx_pack[t];
    int e; float p;
    if (n & 1) { e = pk >> 8; p = p2[t]; } else { e = pk & 0xff; p = p1[t]; }
    int pos = off[e]++;
    if (pos < CAP) {
      size_t o = (size_t)t * EE * CAP + (size_t)e * CAP + pos;
      disp[o] = 1.0f;
      comb[o] = p;
    }
  }
  if (tid == 0) {
    float aux = 0.f;
    for (int e = 0; e < EE; ++e)
      aux += (psum[e] / (float)NTOK) * ((float)tot[e] / (float)NASSIGN);
    aux_out[0] = aux * (float)EE;
  }
}

extern "C" void kernel_launch(void* const* d_in, const int* in_sizes, int n_in,
                              void* d_out, int out_size, void* d_ws, size_t ws_size,
                              hipStream_t stream) {
  const float* x   = (const float*)d_in[0];
  const float* w1  = (const float*)d_in[1];
  const float* b1  = (const float*)d_in[2];
  const float* w2  = (const float*)d_in[3];
  const float* b2  = (const float*)d_in[4];
  const float* wc1 = (const float*)d_in[5];
  const float* bc1 = (const float*)d_in[6];
  const float* wc2 = (const float*)d_in[7];
  const float* bc2 = (const float*)d_in[8];
  const float* chr = (const float*)d_in[9];

  float* out = (float*)d_out;
  float* disp  = out;
  float* comb  = disp + (size_t)NTOK * EE * CAP;
  float* probs = comb + (size_t)NTOK * EE * CAP;
  float* aux   = probs + (size_t)NTOK * EE;

  float* ws = (float*)d_ws;
  float* psum   = ws + WS_PSUM;
  float* hcr    = ws + WS_HC;
  float* adj    = ws + WS_ADJ;
  float* p1     = ws + WS_P1;
  float* p2     = ws + WS_P2;
  int*   idxp   = (int*)(ws + WS_IDX);
  float* logits = ws + WS_LOGITS;           // fallback only
  float* avgp   = ws + WS_LOGITS;           // avg partials (mfma + fallback pre-gemm)

  char* wsb = (char*)d_ws;
  unsigned short* Xh = (unsigned short*)(wsb + WS_BF16_BYTE);
  unsigned short* Xm = Xh + (size_t)NTOK * HH;
  unsigned short* Xl = Xm + (size_t)NTOK * HH;
  unsigned short* Wh = Xl + (size_t)NTOK * HH;
  unsigned short* Wm = Wh + (size_t)HH * HH;
  unsigned short* Wl = Wm + (size_t)HH * HH;
  float* hbuf = (float*)(wsb + WS_H_BYTE);

  bool use_mfma = ws_size >= WS_NEED;

  if (use_mfma) {
    // D1: prep_x + prep_w + avg partials + ws-head zero, one dispatch
    k_prep<<<PREPX_BLKS + PREPW_BLKS + AVG_BLKS, 256, 0, stream>>>(
        x, w1, Xh, Xm, Xl, Wh, Wm, Wl, ws, avgp);
    // D2: hc (atomics into hc_raw zeroed in D1)
    k_hc<<<dim3(HH / 256, 8, BB), 256, 0, stream>>>(avgp, chr, wc1, hcr);
    // D3: 512 GEMM blocks (in-loop NT zeroing of disp/comb) + 2 adj blocks
    k_gemm_mfma<<<dim3(NTOK / BM, HH / BN + 1), 256, 0, stream>>>(
        Xh, Xm, Xl, Wh, Wm, Wl, b1, hbuf, (f32x4*)d_out,
        hcr, bc1, wc2, bc2, adj);
    // D4: logits + softmax + top2 + psum
    k_logits<<<NTOK / 4, 256, 0, stream>>>(hbuf, w2, b2, adj, probs, idxp, p1, p2, psum);
  } else {
    hipMemsetAsync(d_ws, 0, WS_ZERO_BYTES, stream);
    hipMemsetAsync(d_out, 0, (size_t)out_size * sizeof(float), stream);
    k_avgp<<<dim3(HH / 256, 16, BB), 256, 0, stream>>>(x, avgp);
    k_hc<<<dim3(HH / 256, 8, BB), 256, 0, stream>>>(avgp, chr, wc1, hcr);
    k_adj<<<BB, 256, 0, stream>>>(hcr, bc1, wc2, bc2, adj);
    k_init_logits<<<(NTOK * EE) / 256, 256, 0, stream>>>(adj, b2, logits);
    k_gemm_f32<<<dim3(NTOK / 64, HH / 64), 256, 0, stream>>>(x, w1, b1, w2, logits);
    k_softmax<<<NTOK / 256, 256, 0, stream>>>(logits, probs, idxp, p1, p2, psum);
    k_route<<<1, 256, 0, stream>>>(idxp, p1, p2, psum, disp, comb, aux);
  }
  // D5: serial-order capacity + scatter + aux
  if (use_mfma)
    k_route<<<1, 256, 0, stream>>>(idxp, p1, p2, psum, disp, comb, aux);
}